// Round 1
// baseline (843.902 us; speedup 1.0000x reference)
//
#include <hip/hip_runtime.h>
#include <hip/hip_cooperative_groups.h>

namespace cg = cooperative_groups;

// Problem constants (fixed by the reference):
//   B=8, S=4096, D=1024, G=64, H_SEQ=2048, TOP_K=8
#define BB 8
#define SS 4096
#define DD 1024
#define D4 256            // D/4 float4s per row
#define GG 64
#define HH 2048
#define SCALE 0.03125f    // D^-0.5 = 1/32
#define BSD (8L * 4096L * 1024L)

// fused-kernel geometry
#define NBLK 1024         // 4 blocks/CU on 256 CUs -> co-resident for grid.sync
#define NCH 128           // h chunks (one per block): HH/NCH = 16 rows each
#define ROWS_PER_CH (HH / NCH)
#define NPROBE 16         // blocks 0..15: (b, which) probes
#define NCOPY (NBLK - NPROBE)
#define TOTROWS (BB * SS) // 32768

// legacy-path geometry
#define NCHL 64

__device__ __forceinline__ float sigmoidf_(float x) {
    return 1.0f / (1.0f + expf(-x));
}

// ---------------------------------------------------------------------------
// Fused cooperative kernel.
//  Phase A (all blocks): h partial sums.
//  Phase B: blocks 0..15 -> probe (b = bid>>1, which = bid&1), writes sur[16];
//           blocks 16..1023 -> bulk copy K_curr/V_curr -> outK/outV.
//  Phase C: blocks 0..511 -> gated blend of one active row (b = bid>>6,
//           g = bid&63), gates computed inline; momentum written by (g==0,t==0).
// ---------------------------------------------------------------------------
__global__ __launch_bounds__(256, 4) void fused_kernel(
        const float* __restrict__ K_curr, const float* __restrict__ V_curr,
        const float* __restrict__ K_prev, const float* __restrict__ V_prev,
        const float* __restrict__ h, const float* __restrict__ momentum,
        const int* __restrict__ active_idx,
        const float* __restrict__ Wk, const float* __restrict__ bk,
        const float* __restrict__ Wv, const float* __restrict__ bv,
        const float* __restrict__ logit_eta, const float* __restrict__ alpha_logit,
        float* __restrict__ partial, float* __restrict__ sur,
        float* __restrict__ outK, float* __restrict__ outV,
        float* __restrict__ outM) {
    cg::grid_group grid = cg::this_grid();
    int bid = blockIdx.x;
    int t = threadIdx.x;

    // ---- Phase A: h partial reduction (all 1024 blocks, 16 rows each) ----
    {
        int b  = bid >> 7;       // / NCH
        int ch = bid & (NCH - 1);
        const float4* h4 = (const float4*)h;
        long base = ((long)b * HH + (long)ch * ROWS_PER_CH) * D4 + t;
        float4 acc = make_float4(0.f, 0.f, 0.f, 0.f);
#pragma unroll
        for (int i = 0; i < ROWS_PER_CH; ++i) {
            float4 v = h4[base + (long)i * D4];
            acc.x += v.x; acc.y += v.y; acc.z += v.z; acc.w += v.w;
        }
        ((float4*)partial)[(long)bid * D4 + t] = acc;
    }
    grid.sync();

    // ---- Phase B ----
    if (bid < NPROBE) {
        // probe for (b, which)
        __shared__ float q[DD];
        __shared__ float lg[GG];
        __shared__ float attn[GG];
        __shared__ float red[4];
        __shared__ int aidx[GG];

        int b = bid >> 1;
        int which = bid & 1;
        const float* X = which ? V_curr : K_curr;
        int wave = t >> 6;
        int lane = t & 63;

        if (t < GG) aidx[t] = active_idx[b * GG + t];

        // q_probe = mean over H (finish from partials)
        float4 acc = make_float4(0.f, 0.f, 0.f, 0.f);
        const float4* p4 = (const float4*)partial;
#pragma unroll 8
        for (int ch = 0; ch < NCH; ++ch) {
            float4 v = p4[(long)(b * NCH + ch) * D4 + t];
            acc.x += v.x; acc.y += v.y; acc.z += v.z; acc.w += v.w;
        }
        const float invH = 1.0f / (float)HH;
        acc.x *= invH; acc.y *= invH; acc.z *= invH; acc.w *= invH;
        ((float4*)q)[t] = acc;
        __syncthreads();

        // logits: each wave handles 16 g's; float4-vectorized dot over D
        const float4* q4 = (const float4*)q;
        for (int gi = 0; gi < 16; ++gi) {
            int g = wave * 16 + gi;
            int idx = aidx[g];
            const float4* row4 = (const float4*)(X + ((long)b * SS + idx) * DD);
            float s = 0.f;
#pragma unroll
            for (int j = 0; j < 4; ++j) {
                float4 rv = row4[lane + 64 * j];
                float4 qv = q4[lane + 64 * j];
                s += rv.x * qv.x + rv.y * qv.y + rv.z * qv.z + rv.w * qv.w;
            }
#pragma unroll
            for (int off = 32; off >= 1; off >>= 1) s += __shfl_xor(s, off);
            if (lane == 0) lg[g] = s * SCALE;
        }
        __syncthreads();

        // softmax over 64 logits (wave 0)
        if (t < 64) {
            float x = lg[t];
            float m = x;
#pragma unroll
            for (int off = 32; off >= 1; off >>= 1) m = fmaxf(m, __shfl_xor(m, off));
            float e = expf(x - m);
            float ssum = e;
#pragma unroll
            for (int off = 32; off >= 1; off >>= 1) ssum += __shfl_xor(ssum, off);
            attn[t] = e / ssum;
        }
        __syncthreads();

        // pred + surprise
        const float4* X4 = (const float4*)(X + (long)b * SS * DD);
        float4 pred = make_float4(0.f, 0.f, 0.f, 0.f);
        for (int g = 0; g < GG; ++g) {
            int idx = aidx[g];
            float a = attn[g];
            float4 xv = X4[(long)idx * D4 + t];
            pred.x += a * xv.x; pred.y += a * xv.y;
            pred.z += a * xv.z; pred.w += a * xv.w;
        }
        float4 qv = ((const float4*)q)[t];
        float dx = pred.x - qv.x, dy = pred.y - qv.y;
        float dz = pred.z - qv.z, dw = pred.w - qv.w;
        float ss = dx * dx + dy * dy + dz * dz + dw * dw;
#pragma unroll
        for (int off = 32; off >= 1; off >>= 1) ss += __shfl_xor(ss, off);
        if (lane == 0) red[wave] = ss;
        __syncthreads();
        if (t == 0) sur[bid] = (red[0] + red[1] + red[2] + red[3]) / (float)DD;
    } else {
        // bulk copy (active rows get overwritten in phase C)
        const float4* kc4 = (const float4*)K_curr;
        const float4* vc4 = (const float4*)V_curr;
        float4* ok4 = (float4*)outK;
        float4* ov4 = (float4*)outV;
        for (int r = bid - NPROBE; r < TOTROWS; r += NCOPY) {
            long off = (long)r * D4 + t;
            ok4[off] = kc4[off];
            ov4[off] = vc4[off];
        }
    }
    grid.sync();

    // ---- Phase C: gated blend of active rows ----
    if (bid < BB * GG) {
        int b = bid >> 6;
        int g = bid & 63;
        float ks = sur[2 * b + 0];
        float vs = sur[2 * b + 1];
        float alpha = sigmoidf_(alpha_logit[0]);
        float eta   = sigmoidf_(logit_eta[0]);
        float combined = alpha * ks + (1.0f - alpha) * vs;
        float new_m = eta * momentum[b] + (1.0f - eta) * combined;
        if (g == 0 && t == 0) outM[b] = new_m;
        float gk = sigmoidf_(Wk[g * 2 + 0] * ks + Wk[g * 2 + 1] * new_m + bk[g]);
        float gv = sigmoidf_(Wv[g * 2 + 0] * vs + Wv[g * 2 + 1] * new_m + bv[g]);
        int idx = active_idx[b * GG + g];
        long off = ((long)b * SS + idx) * D4 + t;
        float4 kc = ((const float4*)K_curr)[off];
        float4 kp = ((const float4*)K_prev)[off];
        float4 vc = ((const float4*)V_curr)[off];
        float4 vp = ((const float4*)V_prev)[off];
        float4 ko, vo;
        ko.x = gk * kc.x + (1.0f - gk) * kp.x;
        ko.y = gk * kc.y + (1.0f - gk) * kp.y;
        ko.z = gk * kc.z + (1.0f - gk) * kp.z;
        ko.w = gk * kc.w + (1.0f - gk) * kp.w;
        vo.x = gv * vc.x + (1.0f - gv) * vp.x;
        vo.y = gv * vc.y + (1.0f - gv) * vp.y;
        vo.z = gv * vc.z + (1.0f - gv) * vp.z;
        vo.w = gv * vc.w + (1.0f - gv) * vp.w;
        ((float4*)outK)[off] = ko;
        ((float4*)outV)[off] = vo;
    }
}

// ===========================================================================
// Legacy fallback pipeline (the previously-verified 3-kernel version),
// used only if the cooperative launch is rejected at runtime.
// ===========================================================================
__global__ __launch_bounds__(256) void reduce_h_legacy(const float* __restrict__ h,
                                                       float* __restrict__ partial) {
    int blk = blockIdx.x;
    int b  = blk >> 6;
    int ch = blk & 63;
    int t  = threadIdx.x;
    const float4* h4 = (const float4*)h;
    int sbase = ch * (HH / NCHL);
    long base = ((long)b * HH + sbase) * D4 + t;
    float4 acc = make_float4(0.f, 0.f, 0.f, 0.f);
#pragma unroll 4
    for (int i = 0; i < HH / NCHL; ++i) {
        float4 v = h4[base + (long)i * D4];
        acc.x += v.x; acc.y += v.y; acc.z += v.z; acc.w += v.w;
    }
    ((float4*)partial)[(long)blk * D4 + t] = acc;
}

__global__ __launch_bounds__(256) void probe_legacy(
        const float* __restrict__ K_curr, const float* __restrict__ V_curr,
        const float* __restrict__ momentum, const int* __restrict__ active_idx,
        const float* __restrict__ Wk, const float* __restrict__ bk,
        const float* __restrict__ Wv, const float* __restrict__ bv,
        const float* __restrict__ logit_eta, const float* __restrict__ alpha_logit,
        const float* __restrict__ partial,
        float* __restrict__ gate_k, float* __restrict__ gate_v,
        float* __restrict__ out_m) {
    int b = blockIdx.x;
    int t = threadIdx.x;
    int wave = t >> 6;
    int lane = t & 63;

    __shared__ float q[DD];
    __shared__ float lg[GG];
    __shared__ float attn[GG];
    __shared__ float red[4];
    __shared__ float s_sur[2];

    float4 acc = make_float4(0.f, 0.f, 0.f, 0.f);
    const float4* p4 = (const float4*)partial;
#pragma unroll 8
    for (int ch = 0; ch < NCHL; ++ch) {
        float4 v = p4[(long)(b * NCHL + ch) * D4 + t];
        acc.x += v.x; acc.y += v.y; acc.z += v.z; acc.w += v.w;
    }
    const float invH = 1.0f / (float)HH;
    acc.x *= invH; acc.y *= invH; acc.z *= invH; acc.w *= invH;
    ((float4*)q)[t] = acc;
    __syncthreads();

    for (int which = 0; which < 2; ++which) {
        const float* X = which ? V_curr : K_curr;
        for (int gi = 0; gi < 16; ++gi) {
            int g = wave * 16 + gi;
            int idx = active_idx[b * GG + g];
            const float* row = X + ((long)b * SS + idx) * DD;
            float s = 0.f;
#pragma unroll
            for (int j = 0; j < 16; ++j) {
                int d = lane + 64 * j;
                s += q[d] * row[d];
            }
#pragma unroll
            for (int off = 32; off >= 1; off >>= 1) s += __shfl_xor(s, off);
            if (lane == 0) lg[g] = s * SCALE;
        }
        __syncthreads();

        if (t < 64) {
            float x = lg[t];
            float m = x;
#pragma unroll
            for (int off = 32; off >= 1; off >>= 1) m = fmaxf(m, __shfl_xor(m, off));
            float e = expf(x - m);
            float ssum = e;
#pragma unroll
            for (int off = 32; off >= 1; off >>= 1) ssum += __shfl_xor(ssum, off);
            attn[t] = e / ssum;
        }
        __syncthreads();

        const float4* X4 = (const float4*)(X + (long)b * SS * DD);
        float4 pred = make_float4(0.f, 0.f, 0.f, 0.f);
        for (int g = 0; g < GG; ++g) {
            int idx = active_idx[b * GG + g];
            float a = attn[g];
            float4 xv = X4[(long)idx * D4 + t];
            pred.x += a * xv.x; pred.y += a * xv.y;
            pred.z += a * xv.z; pred.w += a * xv.w;
        }
        float4 qv = ((const float4*)q)[t];
        float dx = pred.x - qv.x, dy = pred.y - qv.y;
        float dz = pred.z - qv.z, dw = pred.w - qv.w;
        float ss = dx * dx + dy * dy + dz * dz + dw * dw;
#pragma unroll
        for (int off = 32; off >= 1; off >>= 1) ss += __shfl_xor(ss, off);
        if (lane == 0) red[wave] = ss;
        __syncthreads();
        if (t == 0) s_sur[which] = (red[0] + red[1] + red[2] + red[3]) / (float)DD;
        __syncthreads();
    }

    float ks = s_sur[0], vs = s_sur[1];
    float alpha = sigmoidf_(alpha_logit[0]);
    float eta   = sigmoidf_(logit_eta[0]);
    float combined = alpha * ks + (1.0f - alpha) * vs;
    float new_m = eta * momentum[b] + (1.0f - eta) * combined;
    if (t == 0) out_m[b] = new_m;
    if (t < GG) {
        gate_k[b * GG + t] = sigmoidf_(Wk[t * 2 + 0] * ks + Wk[t * 2 + 1] * new_m + bk[t]);
        gate_v[b * GG + t] = sigmoidf_(Wv[t * 2 + 0] * vs + Wv[t * 2 + 1] * new_m + bv[t]);
    }
}

__global__ __launch_bounds__(256) void scatter_legacy(
        const float* __restrict__ K_curr, const float* __restrict__ V_curr,
        const float* __restrict__ K_prev, const float* __restrict__ V_prev,
        const int* __restrict__ active_idx,
        const float* __restrict__ gate_k, const float* __restrict__ gate_v,
        float* __restrict__ outK, float* __restrict__ outV) {
    int r = blockIdx.x;
    int b = r >> 12;
    int s = r & 4095;
    int t = threadIdx.x;

    __shared__ int aidx[GG];
    if (t < GG) aidx[t] = active_idx[b * GG + t];
    __syncthreads();

    int g = -1;
#pragma unroll
    for (int j = 0; j < GG; ++j)
        if (aidx[j] == s) g = j;

    long off = (long)r * D4 + t;
    float4 kc = ((const float4*)K_curr)[off];
    float4 vc = ((const float4*)V_curr)[off];

    if (g >= 0) {
        float gk = gate_k[b * GG + g];
        float gv = gate_v[b * GG + g];
        float4 kp = ((const float4*)K_prev)[off];
        float4 vp = ((const float4*)V_prev)[off];
        kc.x = gk * kc.x + (1.0f - gk) * kp.x;
        kc.y = gk * kc.y + (1.0f - gk) * kp.y;
        kc.z = gk * kc.z + (1.0f - gk) * kp.z;
        kc.w = gk * kc.w + (1.0f - gk) * kp.w;
        vc.x = gv * vc.x + (1.0f - gv) * vp.x;
        vc.y = gv * vc.y + (1.0f - gv) * vp.y;
        vc.z = gv * vc.z + (1.0f - gv) * vp.z;
        vc.w = gv * vc.w + (1.0f - gv) * vp.w;
    }
    ((float4*)outK)[off] = kc;
    ((float4*)outV)[off] = vc;
}

extern "C" void kernel_launch(void* const* d_in, const int* in_sizes, int n_in,
                              void* d_out, int out_size, void* d_ws, size_t ws_size,
                              hipStream_t stream) {
    const float* K_curr      = (const float*)d_in[0];
    const float* V_curr      = (const float*)d_in[1];
    const float* K_prev      = (const float*)d_in[2];
    const float* V_prev      = (const float*)d_in[3];
    const float* h           = (const float*)d_in[4];
    const float* momentum    = (const float*)d_in[5];
    const int*   active_idx  = (const int*)d_in[6];
    const float* Wk          = (const float*)d_in[7];
    const float* bk          = (const float*)d_in[8];
    const float* Wv          = (const float*)d_in[9];
    const float* bv          = (const float*)d_in[10];
    const float* logit_eta   = (const float*)d_in[11];
    const float* alpha_logit = (const float*)d_in[12];

    float* out = (float*)d_out;
    float* ws  = (float*)d_ws;

    // workspace layout
    float* partial = ws;                               // B*NCH*D = 1048576 floats (4 MB)
    float* sur     = partial + (long)BB * NCH * DD;    // 16 floats
    float* gate_k  = sur + 16;                         // legacy: 512 floats
    float* gate_v  = gate_k + BB * GG;                 // legacy: 512 floats
    float* oldpart = gate_v + BB * GG;                 // legacy: B*NCHL*D floats (2 MB)

    float* outK = out;
    float* outV = out + BSD;
    float* outM = out + 2 * BSD;

    void* args[] = {
        (void*)&K_curr, (void*)&V_curr, (void*)&K_prev, (void*)&V_prev,
        (void*)&h, (void*)&momentum, (void*)&active_idx,
        (void*)&Wk, (void*)&bk, (void*)&Wv, (void*)&bv,
        (void*)&logit_eta, (void*)&alpha_logit,
        (void*)&partial, (void*)&sur,
        (void*)&outK, (void*)&outV, (void*)&outM
    };

    hipError_t err = hipLaunchCooperativeKernel((const void*)fused_kernel,
                                                dim3(NBLK), dim3(256),
                                                args, 0, stream);
    if (err != hipSuccess) {
        // fallback: previously-verified 3-kernel pipeline
        reduce_h_legacy<<<BB * NCHL, 256, 0, stream>>>(h, oldpart);
        probe_legacy<<<BB, 256, 0, stream>>>(K_curr, V_curr, momentum, active_idx,
                                             Wk, bk, Wv, bv, logit_eta, alpha_logit,
                                             oldpart, gate_k, gate_v, outM);
        scatter_legacy<<<BB * SS, 256, 0, stream>>>(K_curr, V_curr, K_prev, V_prev,
                                                    active_idx, gate_k, gate_v,
                                                    outK, outV);
    }
}